// Round 1
// baseline (924.532 us; speedup 1.0000x reference)
//
#include <hip/hip_runtime.h>

// B=2 H=16 S=2048 D=64, fp32 in/out.
// out = [output (2*16*2048*64), attn (2*16*2048*2048)] fp32, concatenated.

constexpr int S = 2048;
constexpr int D = 64;
constexpr int QBLK = 16;     // q rows per block
constexpr int NWAVE = 8;     // 512 threads
constexpr int PA_STRIDE = S + 8;  // bf16 elems; pad spreads b128 reads over banks

typedef __attribute__((ext_vector_type(8))) short bf16x8;
typedef __attribute__((ext_vector_type(4))) float f32x4;

__device__ inline short f2bf(float f) {
  union { float f; unsigned u; } x;
  x.f = f;
  unsigned r = (x.u + 0x7fffu + ((x.u >> 16) & 1u)) >> 16;  // RNE
  return (short)r;
}

__global__ __launch_bounds__(512, 2) void attn_kernel(
    const float* __restrict__ qg, const float* __restrict__ kg,
    const float* __restrict__ vg, const float* __restrict__ sent,
    const int* __restrict__ mask, float* __restrict__ out_o,
    float* __restrict__ out_attn) {
  __shared__ short pa[QBLK * PA_STRIDE];        // bf16 attn tile for PV
  __shared__ float red_max[NWAVE][QBLK];
  __shared__ float red_sum[NWAVE][QBLK];
  __shared__ float po[QBLK * D];                // partial O from k-half 1

  const int qt = blockIdx.x;          // 0..127
  const int bh = blockIdx.y;          // 0..31
  const int b = bh >> 4;
  const int q0 = qt * QBLK;
  const int tid = threadIdx.x;
  const int wid = tid >> 6;
  const int lane = tid & 63;
  const int l15 = lane & 15;
  const int l4 = lane >> 4;           // 0..3
  const int row_base = l4 * 4;        // D-frag rows row_base..row_base+3

  const long bh_off = (long)bh * S;   // row offset into [BH*S][D]

  // ---------------- Phase 1: scores = (Q/8)·K^T via MFMA ----------------
  bf16x8 qf[2];
  {
    const float* qrow = qg + (bh_off + q0 + l15) * D + l4 * 8;
#pragma unroll
    for (int ks = 0; ks < 2; ++ks) {
      f32x4 a = *(const f32x4*)(qrow + ks * 32);
      f32x4 c = *(const f32x4*)(qrow + ks * 32 + 4);
#pragma unroll
      for (int j = 0; j < 4; ++j) {
        qf[ks][j]     = f2bf(a[j] * 0.125f);
        qf[ks][j + 4] = f2bf(c[j] * 0.125f);
      }
    }
  }

  const int n_base = wid * 256;       // this wave's 256-key strip
  f32x4 acc[16];
#pragma unroll
  for (int nt = 0; nt < 16; ++nt) {
    acc[nt] = f32x4{0.f, 0.f, 0.f, 0.f};
    const float* krow = kg + (bh_off + n_base + nt * 16 + l15) * D + l4 * 8;
#pragma unroll
    for (int ks = 0; ks < 2; ++ks) {
      f32x4 a = *(const f32x4*)(krow + ks * 32);
      f32x4 c = *(const f32x4*)(krow + ks * 32 + 4);
      bf16x8 kf;
#pragma unroll
      for (int j = 0; j < 4; ++j) {
        kf[j]     = f2bf(a[j]);
        kf[j + 4] = f2bf(c[j]);
      }
      acc[nt] = __builtin_amdgcn_mfma_f32_16x16x32_bf16(qf[ks], kf, acc[nt], 0, 0, 0);
    }
  }

  // ---------------- Phase 2: fused softmax * sent_att, renorm ----------------
  // attn_k = mask_k * exp(s_k - m) * sent_k / sum_j(mask_j * exp(s_j - m) * sent_j)
  float pm[4];
#pragma unroll
  for (int r = 0; r < 4; ++r) {
    float mx = acc[0][r];
#pragma unroll
    for (int nt = 1; nt < 16; ++nt) mx = fmaxf(mx, acc[nt][r]);
    pm[r] = mx;
  }
#pragma unroll
  for (int r = 0; r < 4; ++r) {
#pragma unroll
    for (int s = 1; s < 16; s <<= 1)
      pm[r] = fmaxf(pm[r], __shfl_xor(pm[r], s, 64));
  }
  if (l15 == 0) {
#pragma unroll
    for (int r = 0; r < 4; ++r) red_max[wid][row_base + r] = pm[r];
  }
  __syncthreads();
  float m[4];
#pragma unroll
  for (int r = 0; r < 4; ++r) {
    float mx = red_max[0][row_base + r];
#pragma unroll
    for (int w = 1; w < NWAVE; ++w) mx = fmaxf(mx, red_max[w][row_base + r]);
    m[r] = mx;
  }

  float pd[4] = {0.f, 0.f, 0.f, 0.f};
#pragma unroll
  for (int nt = 0; nt < 16; ++nt) {
    const int col = n_base + nt * 16 + l15;
    const float sa = sent[b * S + col];
    const int mk = mask[b * S + col];
    const float scale = mk ? sa : 0.f;
#pragma unroll
    for (int r = 0; r < 4; ++r) {
      float t = __expf(acc[nt][r] - m[r]) * scale;  // <=exp(0), no overflow
      acc[nt][r] = t;
      pd[r] += t;
    }
  }
#pragma unroll
  for (int r = 0; r < 4; ++r) {
#pragma unroll
    for (int s = 1; s < 16; s <<= 1) pd[r] += __shfl_xor(pd[r], s, 64);
  }
  if (l15 == 0) {
#pragma unroll
    for (int r = 0; r < 4; ++r) red_sum[wid][row_base + r] = pd[r];
  }
  __syncthreads();
  float inv[4];
#pragma unroll
  for (int r = 0; r < 4; ++r) {
    float sm = red_sum[0][row_base + r];
#pragma unroll
    for (int w = 1; w < NWAVE; ++w) sm += red_sum[w][row_base + r];
    inv[r] = 1.0f / sm;
  }

  // write fp32 attn to global, bf16 attn to LDS for PV
  const long attn_row0 = bh_off + q0;
#pragma unroll
  for (int nt = 0; nt < 16; ++nt) {
    const int col = n_base + nt * 16 + l15;
#pragma unroll
    for (int r = 0; r < 4; ++r) {
      const int row = row_base + r;
      const float a = acc[nt][r] * inv[r];
      out_attn[(attn_row0 + row) * (long)S + col] = a;
      pa[row * PA_STRIDE + col] = f2bf(a);
    }
  }
  __syncthreads();  // PV reads other waves' pa columns

  // ---------------- Phase 3: O = attn · V via MFMA ----------------
  const int dt = wid & 3;             // d-tile 0..3 (16 cols each)
  const int kh = wid >> 2;            // k-half 0/1 (1024 keys each)
  const int d0 = dt * 16;
  f32x4 acco = {0.f, 0.f, 0.f, 0.f};
  const int kbase0 = kh * 1024;
#pragma unroll 4
  for (int kk = 0; kk < 32; ++kk) {
    const int kpos = kbase0 + kk * 32 + l4 * 8;
    bf16x8 paf = *(const bf16x8*)&pa[l15 * PA_STRIDE + kpos];
    const float* vrow = vg + (bh_off + kpos) * D + d0 + l15;
    bf16x8 vf;
#pragma unroll
    for (int j = 0; j < 8; ++j) vf[j] = f2bf(vrow[j * D]);
    acco = __builtin_amdgcn_mfma_f32_16x16x32_bf16(paf, vf, acco, 0, 0, 0);
  }

  if (kh == 1) {
#pragma unroll
    for (int r = 0; r < 4; ++r) po[(row_base + r) * D + d0 + l15] = acco[r];
  }
  __syncthreads();
  if (kh == 0) {
#pragma unroll
    for (int r = 0; r < 4; ++r) {
      const float val = acco[r] + po[(row_base + r) * D + d0 + l15];
      out_o[(attn_row0 + row_base + r) * (long)D + d0 + l15] = val;
    }
  }
}

extern "C" void kernel_launch(void* const* d_in, const int* in_sizes, int n_in,
                              void* d_out, int out_size, void* d_ws, size_t ws_size,
                              hipStream_t stream) {
  const float* q = (const float*)d_in[0];
  const float* k = (const float*)d_in[1];
  const float* v = (const float*)d_in[2];
  const float* sent = (const float*)d_in[3];
  const int* mask = (const int*)d_in[4];
  float* out = (float*)d_out;
  float* out_o = out;                          // [2,16,2048,64]
  float* out_attn = out + (long)2 * 16 * S * D;  // [2,16,2048,2048]

  dim3 grid(S / QBLK, 32);  // (q-tile, b*h)
  attn_kernel<<<grid, NWAVE * 64, 0, stream>>>(q, k, v, sent, mask, out_o, out_attn);
}